// Round 7
// baseline (596.060 us; speedup 1.0000x reference)
//
#include <hip/hip_runtime.h>
#include <hip/hip_cooperative_groups.h>
namespace cg = cooperative_groups;

#define RES  32
#define R3   32768          // RES^3
#define NBLK 256            // 1 block per CU (128KB LDS forces it)
#define NTHR 1024

struct Params {
    const float* feats;     // (B, D, N)
    const float* coords;    // (B, 3, N)
    float* vox;             // (B, D, R3)
    float* nc;              // (B, 3, N)
    float* accum;           // B*4
    unsigned* maxsq;        // B
    int* counts;            // B*R3
    unsigned short* start;  // B*R3  exclusive-scan offsets
    int* cursor;            // B*R3  scatter cursors
    unsigned* keys;         // B*N   (voxid<<16)|pid, point order
    unsigned* skeys;        // B*N   same, voxel-sorted
    int B, D, N;
};

__global__ __launch_bounds__(NTHR, 4) void fused_kernel(Params p) {
    cg::grid_group grid = cg::this_grid();
    const int tid = threadIdx.x;
    const int bid = blockIdx.x;
    const int B = p.B, D = p.D, N = p.N;
    const int lane = tid & 63, wv = tid >> 6;

    __shared__ float row[R3];                 // 128 KB: staged feature row
    __shared__ float red[3][16];
    __shared__ unsigned short headv[NTHR];    // carry-chain: head voxel id
    __shared__ float headsum[NTHR];           // carry-chain: head partial sum
    __shared__ unsigned char contf[NTHR];     // head run reaches chunk end
    __shared__ int wsum[16], woff[16];

    // ---------------- P0: zero counts / accum / maxsq ----------------
    {
        const int gtid = bid * NTHR + tid, gsz = NBLK * NTHR;
        int4* c4 = (int4*)p.counts;
        const int tot4 = (B * R3) >> 2;
        for (int i = gtid; i < tot4; i += gsz) c4[i] = make_int4(0, 0, 0, 0);
        if (bid == 0) {
            if (tid < B * 4) p.accum[tid] = 0.f;
            if (tid >= 256 && tid < 256 + B) p.maxsq[tid - 256] = 0u;
        }
    }
    grid.sync();

    const int b1 = bid % B;                 // batch handled in wide phases
    const int chunk = bid / B;              // 16 chunks per batch
    const int pstride = (NBLK / B) * NTHR;
    const float* cb = p.coords + (size_t)b1 * 3 * N;
    const int nvec = N >> 2;
    const float4* c0 = (const float4*)cb;
    const float4* c1 = (const float4*)(cb + N);
    const float4* c2 = (const float4*)(cb + 2 * N);

    // ---------------- P1: coordinate sums ----------------
    {
        float s0 = 0.f, s1 = 0.f, s2 = 0.f;
        for (int n = chunk * NTHR + tid; n < nvec; n += pstride) {
            float4 a = c0[n]; s0 += (a.x + a.y) + (a.z + a.w);
            float4 c = c1[n]; s1 += (c.x + c.y) + (c.z + c.w);
            float4 d = c2[n]; s2 += (d.x + d.y) + (d.z + d.w);
        }
        if (chunk == 0 && tid == 0)
            for (int n = nvec << 2; n < N; ++n) { s0 += cb[n]; s1 += cb[N + n]; s2 += cb[2 * N + n]; }
        for (int o = 32; o; o >>= 1) {
            s0 += __shfl_down(s0, o); s1 += __shfl_down(s1, o); s2 += __shfl_down(s2, o);
        }
        if (lane == 0) { red[0][wv] = s0; red[1][wv] = s1; red[2][wv] = s2; }
        __syncthreads();
        if (tid == 0) {
            float t0 = 0.f, t1 = 0.f, t2 = 0.f;
            for (int w = 0; w < 16; ++w) { t0 += red[0][w]; t1 += red[1][w]; t2 += red[2][w]; }
            unsafeAtomicAdd(&p.accum[b1 * 4 + 0], t0);
            unsafeAtomicAdd(&p.accum[b1 * 4 + 1], t1);
            unsafeAtomicAdd(&p.accum[b1 * 4 + 2], t2);
        }
        __syncthreads();
    }
    grid.sync();

    const float m0 = p.accum[b1 * 4 + 0] / (float)N;
    const float m1 = p.accum[b1 * 4 + 1] / (float)N;
    const float m2 = p.accum[b1 * 4 + 2] / (float)N;

    // ---------------- P2: max centered norm^2 ----------------
    {
        float mx = 0.f;
        for (int n = chunk * NTHR + tid; n < nvec; n += pstride) {
            float4 a = c0[n], c = c1[n], d = c2[n];
            a.x -= m0; a.y -= m0; a.z -= m0; a.w -= m0;
            c.x -= m1; c.y -= m1; c.z -= m1; c.w -= m1;
            d.x -= m2; d.y -= m2; d.z -= m2; d.w -= m2;
            mx = fmaxf(mx, a.x * a.x + c.x * c.x + d.x * d.x);
            mx = fmaxf(mx, a.y * a.y + c.y * c.y + d.y * d.y);
            mx = fmaxf(mx, a.z * a.z + c.z * c.z + d.z * d.z);
            mx = fmaxf(mx, a.w * a.w + c.w * c.w + d.w * d.w);
        }
        if (chunk == 0 && tid == 0)
            for (int n = nvec << 2; n < N; ++n) {
                float a = cb[n] - m0, c = cb[N + n] - m1, d = cb[2 * N + n] - m2;
                mx = fmaxf(mx, a * a + c * c + d * d);
            }
        for (int o = 32; o; o >>= 1) mx = fmaxf(mx, __shfl_down(mx, o));
        if (lane == 0) red[0][wv] = mx;
        __syncthreads();
        if (tid == 0) {
            for (int w = 0; w < 16; ++w) mx = fmaxf(mx, red[0][w]);
            atomicMax(&p.maxsq[b1], __float_as_uint(mx));
        }
        __syncthreads();
    }
    grid.sync();

    // ---------------- P3: normalize, nc out, keys, counts ----------------
    {
        const float denom = 2.0f * sqrtf(__uint_as_float(p.maxsq[b1]));
        float* ncb = p.nc + (size_t)b1 * 3 * N;
        unsigned* krow = p.keys + (size_t)b1 * N;
        int* crow = p.counts + (size_t)b1 * R3;
        for (int n4 = chunk * NTHR + tid; n4 < nvec; n4 += pstride) {
            const int n0 = n4 << 2;
            float4 a = c0[n4], c = c1[n4], d = c2[n4];
            float4 v0, v1, v2; int4 id;
            #define PROC(comp)                                                    \
            {                                                                     \
                float x = (a.comp - m0) / denom + 0.5f;                           \
                float y = (c.comp - m1) / denom + 0.5f;                           \
                float z = (d.comp - m2) / denom + 0.5f;                           \
                v0.comp = fminf(fmaxf(x * (float)RES, 0.f), (float)(RES - 1));    \
                v1.comp = fminf(fmaxf(y * (float)RES, 0.f), (float)(RES - 1));    \
                v2.comp = fminf(fmaxf(z * (float)RES, 0.f), (float)(RES - 1));    \
                id.comp = (int)rintf(v0.comp) * RES * RES                         \
                        + (int)rintf(v1.comp) * RES + (int)rintf(v2.comp);        \
            }
            PROC(x) PROC(y) PROC(z) PROC(w)
            #undef PROC
            *(float4*)(ncb + n0) = v0;
            *(float4*)(ncb + N + n0) = v1;
            *(float4*)(ncb + 2 * N + n0) = v2;
            uint4 k;
            k.x = ((unsigned)id.x << 16) | (unsigned)(n0 + 0);
            k.y = ((unsigned)id.y << 16) | (unsigned)(n0 + 1);
            k.z = ((unsigned)id.z << 16) | (unsigned)(n0 + 2);
            k.w = ((unsigned)id.w << 16) | (unsigned)(n0 + 3);
            *(uint4*)(krow + n0) = k;
            atomicAdd(&crow[id.x], 1);
            atomicAdd(&crow[id.y], 1);
            atomicAdd(&crow[id.z], 1);
            atomicAdd(&crow[id.w], 1);
        }
        if (chunk == 0 && tid == 0) {
            for (int n = nvec << 2; n < N; ++n) {
                float x = (cb[n] - m0) / denom + 0.5f;
                float y = (cb[N + n] - m1) / denom + 0.5f;
                float z = (cb[2 * N + n] - m2) / denom + 0.5f;
                float v0 = fminf(fmaxf(x * (float)RES, 0.f), (float)(RES - 1));
                float v1 = fminf(fmaxf(y * (float)RES, 0.f), (float)(RES - 1));
                float v2 = fminf(fmaxf(z * (float)RES, 0.f), (float)(RES - 1));
                ncb[n] = v0; ncb[N + n] = v1; ncb[2 * N + n] = v2;
                int id = (int)rintf(v0) * RES * RES + (int)rintf(v1) * RES + (int)rintf(v2);
                krow[n] = ((unsigned)id << 16) | (unsigned)n;
                atomicAdd(&crow[id], 1);
            }
        }
    }
    grid.sync();

    // ---------------- P4: exclusive scan (blocks 0..B-1) ----------------
    if (bid < B) {
        const int* crow = p.counts + (size_t)bid * R3;
        int vals[32]; int tot = 0;
        const int4* c4 = (const int4*)(crow + tid * 32);
        for (int i = 0; i < 8; ++i) {
            int4 t = c4[i];
            vals[4 * i + 0] = t.x; vals[4 * i + 1] = t.y;
            vals[4 * i + 2] = t.z; vals[4 * i + 3] = t.w;
            tot += (t.x + t.y) + (t.z + t.w);
        }
        int inc = tot;
        for (int o = 1; o < 64; o <<= 1) {
            int t = __shfl_up(inc, o);
            if (lane >= o) inc += t;
        }
        if (lane == 63) wsum[wv] = inc;
        __syncthreads();
        if (tid == 0) { int r = 0; for (int w = 0; w < 16; ++w) { woff[w] = r; r += wsum[w]; } }
        __syncthreads();
        int run = woff[wv] + inc - tot;
        unsigned short* srow = p.start + (size_t)bid * R3 + tid * 32;
        int* urow = p.cursor + (size_t)bid * R3 + tid * 32;
        for (int i = 0; i < 32; ++i) {
            srow[i] = (unsigned short)run;
            urow[i] = run;
            run += vals[i];
        }
    }
    grid.sync();

    // ---------------- P5: counting-sort scatter of keys ----------------
    {
        const unsigned* krow = p.keys + (size_t)b1 * N;
        unsigned* skrow = p.skeys + (size_t)b1 * N;
        int* curs = p.cursor + (size_t)b1 * R3;
        for (int n = chunk * NTHR + tid; n < N; n += pstride) {
            unsigned key = krow[n];
            int pos = atomicAdd(&curs[key >> 16], 1);
            skrow[pos] = key;
        }
    }
    grid.sync();

    // ---------------- P6: balanced segmented reduce, 4 tiles/block ------
    const int tiles = B * D;
    const int PPT = (N + NTHR - 1) / NTHR;   // 32 for N=32768
    for (int tile = bid; tile < tiles; tile += NBLK) {
        const int b = tile / D, d = tile % D;
        __syncthreads();   // protect headv/row from previous tile's readers
        {
            const float* frow = p.feats + ((size_t)b * D + d) * N;
            float4* r4 = (float4*)row;
            const float4* f4 = (const float4*)frow;
            for (int i = tid; i < (N >> 2); i += NTHR) r4[i] = f4[i];
            if (tid == 0) for (int n = (N >> 2) << 2; n < N; ++n) row[n] = frow[n];
        }
        __syncthreads();

        const unsigned* skrow = p.skeys + (size_t)b * N;
        const unsigned short* srow = p.start + (size_t)b * R3;
        const int* crow = p.counts + (size_t)b * R3;
        float* vrow = p.vox + ((size_t)b * D + d) * R3;

        const int p0 = tid * PPT;
        const int pend = min(p0 + PPT, N);

        unsigned cur = 0xFFFFFFFFu;
        float sum = 0.f;
        int seg_start = p0;
        unsigned short hv = 0xFFFFu; float hs = 0.f; unsigned char cont = 0;

        auto step = [&](unsigned key, int gpos) {
            unsigned v = key >> 16;
            float val = row[key & 0xFFFFu];
            if (cur == 0xFFFFFFFFu) { cur = v; sum = val; seg_start = gpos; }
            else if (v == cur) { sum += val; }
            else {
                // flush interior segment [seg_start, gpos)
                if ((int)srow[cur] == seg_start) {
                    int c = crow[cur];
                    vrow[cur] = sum / (float)(c > 1 ? c : 1);
                } else { hv = (unsigned short)cur; hs = sum; }   // unowned head
                cur = v; sum = val; seg_start = gpos;
            }
        };

        if (p0 < N) {
            int g = p0;
            if (((PPT & 7) == 0) && pend == p0 + PPT) {
                for (; g < pend; g += 8) {
                    uint4 k0 = *(const uint4*)(skrow + g);
                    uint4 k1 = *(const uint4*)(skrow + g + 4);
                    step(k0.x, g + 0); step(k0.y, g + 1);
                    step(k0.z, g + 2); step(k0.w, g + 3);
                    step(k1.x, g + 4); step(k1.y, g + 5);
                    step(k1.z, g + 6); step(k1.w, g + 7);
                }
            } else {
                for (; g < pend; ++g) step(skrow[g], g);
            }
        }

        bool tail_owned = false;
        unsigned tv = 0; float ts = 0.f;
        if (p0 < N) {
            if ((int)srow[cur] == seg_start) { tail_owned = true; tv = cur; ts = sum; }
            else { hv = (unsigned short)cur; hs = sum; cont = 1; }  // pass-through
        }
        headv[tid] = hv; headsum[tid] = hs; contf[tid] = cont;
        __syncthreads();
        if (tail_owned) {
            float total = ts;
            for (int u = tid + 1; u < NTHR; ++u) {
                if (headv[u] != (unsigned short)tv) break;
                total += headsum[u];
                if (!contf[u]) break;
            }
            int c = crow[tv];
            vrow[tv] = total / (float)(c > 1 ? c : 1);
        }
        // zero-fill empty voxels (each voxel has exactly one writer)
        for (int i = tid; i < (R3 >> 2); i += NTHR) {
            int4 c = ((const int4*)crow)[i];
            const int v0 = i << 2;
            if (c.x == 0) vrow[v0 + 0] = 0.f;
            if (c.y == 0) vrow[v0 + 1] = 0.f;
            if (c.z == 0) vrow[v0 + 2] = 0.f;
            if (c.w == 0) vrow[v0 + 3] = 0.f;
        }
    }
}

extern "C" void kernel_launch(void* const* d_in, const int* in_sizes, int n_in,
                              void* d_out, int out_size, void* d_ws, size_t ws_size,
                              hipStream_t stream) {
    const float* feats  = (const float*)d_in[0];
    const float* coords = (const float*)d_in[1];
    float* out = (float*)d_out;

    const int D = (int)(3LL * in_sizes[0] / in_sizes[1]);
    const int B = (int)((long long)(out_size - in_sizes[1]) / ((long long)D * R3));
    const int N = in_sizes[1] / (3 * B);

    const size_t BR3 = (size_t)B * R3;
    const size_t BN  = (size_t)B * N;

    Params prm;
    prm.feats  = feats;
    prm.coords = coords;
    prm.vox    = out;
    prm.nc     = out + (size_t)B * D * R3;
    prm.accum  = (float*)d_ws;
    prm.maxsq  = (unsigned*)((char*)d_ws + 1024);
    prm.counts = (int*)((char*)d_ws + 4096);
    prm.start  = (unsigned short*)((char*)d_ws + 4096 + 4 * BR3);
    prm.cursor = (int*)((char*)d_ws + 4096 + 6 * BR3);
    prm.keys   = (unsigned*)((char*)d_ws + 4096 + 10 * BR3);
    prm.skeys  = (unsigned*)((char*)d_ws + 4096 + 10 * BR3 + 4 * BN);
    prm.B = B; prm.D = D; prm.N = N;

    void* args[] = { &prm };
    hipLaunchCooperativeKernel(fused_kernel, dim3(NBLK), dim3(NTHR), args, 0, stream);
}